// Round 1
// baseline (390.047 us; speedup 1.0000x reference)
//
#include <hip/hip_runtime.h>
#include <cmath>

typedef float f32x4 __attribute__((ext_vector_type(4)));
typedef __bf16 bf16x8 __attribute__((ext_vector_type(8)));

#define DEV static __device__ __forceinline__

DEV unsigned short f2bf(float f) {
  unsigned int u = __builtin_bit_cast(unsigned int, f);
  u += 0x7FFFu + ((u >> 16) & 1u);
  return (unsigned short)(u >> 16);
}
DEV float bf2f(unsigned short h) {
  unsigned int u = ((unsigned int)h) << 16;
  return __builtin_bit_cast(float, u);
}
DEV f32x4 mfma16(bf16x8 a, bf16x8 b, f32x4 c) {
  return __builtin_amdgcn_mfma_f32_16x16x32_bf16(a, b, c, 0, 0, 0);
}

constexpr int T_SEQ = 2048;

// ---------------------------------------------------------------- rope table
__global__ __launch_bounds__(256) void build_rope(float2* __restrict__ rope) {
  int gid = blockIdx.x * 256 + threadIdx.x;
  if (gid >= T_SEQ * 64) return;
  int t = gid >> 6, i = gid & 63;
  double inv = pow(10000.0, -((double)(2 * i)) / 128.0);
  double wl = 6.283185307179586 / inv;
  double gm = (4096.0 - wl) / (4096.0 - 128.0);
  gm = gm < 0.0 ? 0.0 : (gm > 1.0 ? 1.0 : gm);
  float f = (float)(gm * inv + (1.0 - gm) * inv * 0.25);
  float th = (float)t * f;
  float s, c;
  sincosf(th, &s, &c);
  rope[gid] = make_float2(c, s);
}

// ------------------------------------------------------------- fp32 -> bf16
__global__ __launch_bounds__(256) void cvt_f32_bf16(const float4* __restrict__ in,
                                                    ushort* __restrict__ out, int n4) {
  int i = blockIdx.x * 256 + threadIdx.x;
  if (i >= n4) return;
  float4 v = in[i];
  unsigned int lo = (unsigned int)f2bf(v.x) | ((unsigned int)f2bf(v.y) << 16);
  unsigned int hi = (unsigned int)f2bf(v.z) | ((unsigned int)f2bf(v.w) << 16);
  *(uint2*)(out + (size_t)i * 4) = make_uint2(lo, hi);
}

// ------------------------------------------ fp32 RxC -> bf16 CxR (transpose)
__global__ __launch_bounds__(256) void tconv(const float* __restrict__ in,
                                             ushort* __restrict__ out, int R, int C) {
  __shared__ ushort tile[64][65];
  int c0 = blockIdx.x * 64, r0 = blockIdx.y * 64;
  int j = threadIdx.x & 63, i0 = threadIdx.x >> 6;
#pragma unroll
  for (int ii = 0; ii < 16; ++ii) {
    int i = i0 + ii * 4;
    tile[i][j] = f2bf(in[(size_t)(r0 + i) * C + c0 + j]);
  }
  __syncthreads();
#pragma unroll
  for (int ii = 0; ii < 16; ++ii) {
    int jr = i0 + ii * 4;
    out[(size_t)(c0 + jr) * R + r0 + j] = tile[j][jr];
  }
}

// ------------------------------------------------- bf16 GEMM: C = A * Bt^T
// A: M x K (row-major bf16), Bt: N x K (row-major bf16), C: M x N
template <int OUT_BF16>
__global__ __launch_bounds__(256) void gemm_bt(const ushort* __restrict__ A,
                                               const ushort* __restrict__ Bt,
                                               void* __restrict__ Cv,
                                               int M, int N, int K) {
  __shared__ ushort lA[128 * 64];  // 16 KB, swizzled
  __shared__ ushort lB[128 * 64];
  const int tid = threadIdx.x;
  const int lane = tid & 63;
  const int w = tid >> 6;
  const int m0 = blockIdx.y * 128;
  const int n0 = blockIdx.x * 128;
  const int wm = (w >> 1) << 6;
  const int wn = (w & 1) << 6;

  f32x4 acc[4][4] = {};

  const int boff = (tid & 7) << 4;  // byte offset within 128B row
  const int r0 = tid >> 3;          // base row (0..31)
  const ushort* gA = A + (size_t)(m0 + r0) * K + (boff >> 1);
  const ushort* gB = Bt + (size_t)(n0 + r0) * K + (boff >> 1);

  for (int k0 = 0; k0 < K; k0 += 64) {
    bf16x8 sa[4], sb[4];
#pragma unroll
    for (int ii = 0; ii < 4; ++ii) {
      sa[ii] = *(const bf16x8*)(gA + (size_t)(32 * ii) * K + k0);
      sb[ii] = *(const bf16x8*)(gB + (size_t)(32 * ii) * K + k0);
    }
    __syncthreads();  // prior compute done before overwrite
#pragma unroll
    for (int ii = 0; ii < 4; ++ii) {
      int row = r0 + 32 * ii;
      int ad = row * 128 + (boff ^ ((row & 7) << 4));
      *(bf16x8*)((char*)lA + ad) = sa[ii];
      *(bf16x8*)((char*)lB + ad) = sb[ii];
    }
    __syncthreads();
#pragma unroll
    for (int kc = 0; kc < 2; ++kc) {
      bf16x8 a[4], bb[4];
#pragma unroll
      for (int mt = 0; mt < 4; ++mt) {
        int row = wm + mt * 16 + (lane & 15);
        int byo = kc * 64 + ((lane >> 4) << 4);
        a[mt] = *(const bf16x8*)((const char*)lA + row * 128 + (byo ^ ((row & 7) << 4)));
      }
#pragma unroll
      for (int nt = 0; nt < 4; ++nt) {
        int row = wn + nt * 16 + (lane & 15);
        int byo = kc * 64 + ((lane >> 4) << 4);
        bb[nt] = *(const bf16x8*)((const char*)lB + row * 128 + (byo ^ ((row & 7) << 4)));
      }
#pragma unroll
      for (int mt = 0; mt < 4; ++mt)
#pragma unroll
        for (int nt = 0; nt < 4; ++nt)
          acc[mt][nt] = mfma16(a[mt], bb[nt], acc[mt][nt]);
    }
  }

  const int rr = (lane >> 4) << 2;
  const int cc = lane & 15;
  if (OUT_BF16) {
    ushort* C = (ushort*)Cv;
#pragma unroll
    for (int mt = 0; mt < 4; ++mt)
#pragma unroll
      for (int nt = 0; nt < 4; ++nt)
#pragma unroll
        for (int j = 0; j < 4; ++j) {
          int r = m0 + wm + mt * 16 + rr + j;
          int c = n0 + wn + nt * 16 + cc;
          C[(size_t)r * N + c] = f2bf(acc[mt][nt][j]);
        }
  } else {
    float* C = (float*)Cv;
#pragma unroll
    for (int mt = 0; mt < 4; ++mt)
#pragma unroll
      for (int nt = 0; nt < 4; ++nt)
#pragma unroll
        for (int j = 0; j < 4; ++j) {
          int r = m0 + wm + mt * 16 + rr + j;
          int c = n0 + wn + nt * 16 + cc;
          C[(size_t)r * N + c] = acc[mt][nt][j];
        }
  }
}

// -------------------------------------- RMSNorm + YaRN RoPE (+scale) epilogue
// one wave per 128-dim vector. q: 4096*16 vectors, k: 4096*4 vectors.
__global__ __launch_bounds__(256) void norm_rope(const ushort* __restrict__ qraw,
                                                 const ushort* __restrict__ kvraw,
                                                 const float* __restrict__ qw,
                                                 const float* __restrict__ kw,
                                                 const float2* __restrict__ rope,
                                                 ushort* __restrict__ qout,
                                                 ushort* __restrict__ kout,
                                                 float attn_scale) {
  const int w = threadIdx.x >> 6, lane = threadIdx.x & 63;
  const int vi = blockIdx.x * 4 + w;
  const ushort* src;
  const float* wt;
  ushort* dst;
  float extra;
  int t, bb;
  if (vi < 65536) {
    int row = vi >> 4, H = vi & 15;
    bb = row >> 11;
    t = row & 2047;
    src = qraw + (size_t)row * 2048 + H * 128 + lane * 2;
    wt = qw;
    extra = attn_scale;
    dst = qout + ((size_t)(bb * 16 + H) * T_SEQ + t) * 128 + lane * 2;
  } else {
    int vi2 = vi - 65536;
    int row = vi2 >> 2, g = vi2 & 3;
    bb = row >> 11;
    t = row & 2047;
    src = kvraw + (size_t)row * 1024 + g * 128 + lane * 2;
    wt = kw;
    extra = 1.f;
    dst = kout + ((size_t)(bb * 4 + g) * T_SEQ + t) * 128 + lane * 2;
  }
  float x0 = bf2f(src[0]), x1 = bf2f(src[1]);
  float ss = x0 * x0 + x1 * x1;
#pragma unroll
  for (int d = 1; d < 64; d <<= 1) ss += __shfl_xor(ss, d, 64);
  float sc = rsqrtf(ss * (1.f / 128.f) + 1.1920929e-7f);
  float w0 = wt[lane * 2], w1 = wt[lane * 2 + 1];
  float xn0 = x0 * sc * w0, xn1 = x1 * sc * w1;
  float p0 = __shfl_xor(xn0, 32, 64), p1 = __shfl_xor(xn1, 32, 64);
  float r0 = lane < 32 ? -p0 : p0;
  float r1 = lane < 32 ? -p1 : p1;
  int i0 = (lane * 2) & 63;
  float2 cs0 = rope[t * 64 + i0];
  float2 cs1 = rope[t * 64 + i0 + 1];
  float o0 = (xn0 * cs0.x + r0 * cs0.y) * extra;
  float o1 = (xn1 * cs1.x + r1 * cs1.y) * extra;
  unsigned int pk = (unsigned int)f2bf(o0) | ((unsigned int)f2bf(o1) << 16);
  *(unsigned int*)dst = pk;
}

// --------------------------------------------- V transpose: (b,t,g,d)->(b,g,d,t)
__global__ __launch_bounds__(256) void tv_kernel(const ushort* __restrict__ kvraw,
                                                 ushort* __restrict__ vt) {
  __shared__ ushort tile[64][65];
  int t0 = blockIdx.x * 64;
  int y = blockIdx.y;  // ((b*4+g)*2 + dh)
  int dh = y & 1, bg = y >> 1;
  int bb = bg >> 2, g = bg & 3;
  int j = threadIdx.x & 63, i0 = threadIdx.x >> 6;
#pragma unroll
  for (int ii = 0; ii < 16; ++ii) {
    int i = i0 + ii * 4;  // t offset
    tile[i][j] = kvraw[(size_t)(bb * T_SEQ + t0 + i) * 1024 + 512 + g * 128 + dh * 64 + j];
  }
  __syncthreads();
#pragma unroll
  for (int ii = 0; ii < 16; ++ii) {
    int jr = i0 + ii * 4;  // d offset
    vt[((size_t)bg * 128 + dh * 64 + jr) * T_SEQ + t0 + j] = tile[j][jr];
  }
}

// ----------------------------------------------------------- flash attention
// grid: (T/128, 16 heads, 2 batch); 4 waves, each owns 32 q rows.
__global__ __launch_bounds__(256) void attn_fwd(const ushort* __restrict__ qh,
                                                const ushort* __restrict__ kh,
                                                const ushort* __restrict__ vt,
                                                ushort* __restrict__ o) {
  const int qt = (int)gridDim.x - 1 - (int)blockIdx.x;  // longest blocks first
  const int H = blockIdx.y;
  const int b = blockIdx.z;
  const int g = H & 3;
  const int tid = threadIdx.x, lane = tid & 63, w = tid >> 6;
  const int q0 = qt * 128;
  const int wrow0 = q0 + w * 32;

  __shared__ ushort lK[64 * 128];   // 16KB swizzled, rows = kv
  __shared__ ushort lV[128 * 64];   // 16KB swizzled, rows = d (V^T)
  __shared__ ushort lP[4 * 32 * 64];  // 16KB swizzled, per-wave 32x64

  bf16x8 qf[2][4];
#pragma unroll
  for (int mt = 0; mt < 2; ++mt) {
    const ushort* qb = qh + ((size_t)(b * 16 + H) * T_SEQ + wrow0 + mt * 16 + (lane & 15)) * 128 +
                       ((lane >> 4) << 3);
#pragma unroll
    for (int kc = 0; kc < 4; ++kc) qf[mt][kc] = *(const bf16x8*)(qb + kc * 32);
  }

  f32x4 oacc[2][8] = {};
  float mrow[2][4], lrow[2][4];
#pragma unroll
  for (int mt = 0; mt < 2; ++mt)
#pragma unroll
    for (int jj = 0; jj < 4; ++jj) {
      mrow[mt][jj] = -INFINITY;
      lrow[mt][jj] = 0.f;
    }

  const ushort* kb = kh + (size_t)(b * 4 + g) * T_SEQ * 128;
  const ushort* vb = vt + (size_t)(b * 4 + g) * 128 * T_SEQ;

  const int kband = (tid & 15) << 4;
  const int vband = (tid & 7) << 4;
  const int jmax = 2 * qt + 1;

  for (int j = 0; j <= jmax; ++j) {
    // stage K (64x128) and V^T (128x64) into swizzled LDS
#pragma unroll
    for (int ii = 0; ii < 4; ++ii) {
      int kr = (tid >> 4) + 16 * ii;
      bf16x8 kv8 = *(const bf16x8*)(kb + (size_t)(j * 64 + kr) * 128 + (kband >> 1));
      *(bf16x8*)((char*)lK + kr * 256 + (kband ^ ((kr & 7) << 4))) = kv8;
      int vr = (tid >> 3) + 32 * ii;
      bf16x8 vv8 = *(const bf16x8*)(vb + (size_t)vr * T_SEQ + j * 64 + (vband >> 1));
      *(bf16x8*)((char*)lV + vr * 128 + (vband ^ ((vr & 7) << 4))) = vv8;
    }
    __syncthreads();

    // S = Q K^T  (per wave: 32 x 64)
    f32x4 s[2][4];
#pragma unroll
    for (int nt = 0; nt < 4; ++nt) {
      bf16x8 kf[4];
      int krow = nt * 16 + (lane & 15);
#pragma unroll
      for (int kc = 0; kc < 4; ++kc) {
        int byo = kc * 64 + ((lane >> 4) << 4);
        kf[kc] = *(const bf16x8*)((const char*)lK + krow * 256 + (byo ^ ((krow & 7) << 4)));
      }
#pragma unroll
      for (int mt = 0; mt < 2; ++mt) {
        f32x4 a = {0.f, 0.f, 0.f, 0.f};
#pragma unroll
        for (int kc = 0; kc < 4; ++kc) a = mfma16(qf[mt][kc], kf[kc], a);
        s[mt][nt] = a;
      }
    }

    // causal mask (only the top two tiles can cross the diagonal)
    if (j >= jmax - 1) {
#pragma unroll
      for (int mt = 0; mt < 2; ++mt)
#pragma unroll
        for (int nt = 0; nt < 4; ++nt)
#pragma unroll
          for (int jj = 0; jj < 4; ++jj) {
            int row = wrow0 + mt * 16 + ((lane >> 4) << 2) + jj;
            int col = j * 64 + nt * 16 + (lane & 15);
            if (col > row) s[mt][nt][jj] = -3.0e38f;
          }
    }

    // online softmax
#pragma unroll
    for (int mt = 0; mt < 2; ++mt)
#pragma unroll
      for (int jj = 0; jj < 4; ++jj) {
        float pm = fmaxf(fmaxf(s[mt][0][jj], s[mt][1][jj]), fmaxf(s[mt][2][jj], s[mt][3][jj]));
#pragma unroll
        for (int d = 1; d < 16; d <<= 1) pm = fmaxf(pm, __shfl_xor(pm, d, 64));
        float mn = fmaxf(mrow[mt][jj], pm);
        float rsc = __expf(mrow[mt][jj] - mn);
        mrow[mt][jj] = mn;
        float ps = 0.f;
#pragma unroll
        for (int nt = 0; nt < 4; ++nt) {
          float p = __expf(s[mt][nt][jj] - mn);
          s[mt][nt][jj] = p;
          ps += p;
        }
#pragma unroll
        for (int d = 1; d < 16; d <<= 1) ps += __shfl_xor(ps, d, 64);
        lrow[mt][jj] = lrow[mt][jj] * rsc + ps;
#pragma unroll
        for (int dt = 0; dt < 8; ++dt) oacc[mt][dt][jj] *= rsc;
      }

    // P -> LDS (bf16, swizzled), per-wave region
#pragma unroll
    for (int mt = 0; mt < 2; ++mt)
#pragma unroll
      for (int nt = 0; nt < 4; ++nt)
#pragma unroll
        for (int jj = 0; jj < 4; ++jj) {
          int prow = mt * 16 + ((lane >> 4) << 2) + jj;
          int pcb = (nt * 16 + (lane & 15)) * 2;
          *(ushort*)((char*)lP + w * 4096 + prow * 128 + (pcb ^ ((prow & 7) << 4))) =
              f2bf(s[mt][nt][jj]);
        }
    __syncthreads();

    // O += P V
#pragma unroll
    for (int kc2 = 0; kc2 < 2; ++kc2) {
      bf16x8 pa[2];
#pragma unroll
      for (int mt = 0; mt < 2; ++mt) {
        int prow = mt * 16 + (lane & 15);
        int pbo = kc2 * 64 + ((lane >> 4) << 4);
        pa[mt] = *(const bf16x8*)((char*)lP + w * 4096 + prow * 128 + (pbo ^ ((prow & 7) << 4)));
      }
#pragma unroll
      for (int dt = 0; dt < 8; ++dt) {
        int vrow = dt * 16 + (lane & 15);
        int vbo = kc2 * 64 + ((lane >> 4) << 4);
        bf16x8 vf = *(const bf16x8*)((char*)lV + vrow * 128 + (vbo ^ ((vrow & 7) << 4)));
#pragma unroll
        for (int mt = 0; mt < 2; ++mt) oacc[mt][dt] = mfma16(pa[mt], vf, oacc[mt][dt]);
      }
    }
    __syncthreads();
  }

  // write O (b, t, H*128+d) bf16
#pragma unroll
  for (int mt = 0; mt < 2; ++mt) {
    float inv[4];
#pragma unroll
    for (int jj = 0; jj < 4; ++jj) inv[jj] = 1.f / lrow[mt][jj];
#pragma unroll
    for (int dt = 0; dt < 8; ++dt)
#pragma unroll
      for (int jj = 0; jj < 4; ++jj) {
        int row = wrow0 + mt * 16 + ((lane >> 4) << 2) + jj;
        int col = H * 128 + dt * 16 + (lane & 15);
        o[(size_t)(b * T_SEQ + row) * 2048 + col] = f2bf(oacc[mt][dt][jj] * inv[jj]);
      }
  }
}

// ---------------------------------------------------------------------------
extern "C" void kernel_launch(void* const* d_in, const int* in_sizes, int n_in,
                              void* d_out, int out_size, void* d_ws, size_t ws_size,
                              hipStream_t stream) {
  (void)in_sizes; (void)n_in; (void)out_size; (void)ws_size;
  const float* x = (const float*)d_in[0];
  const float* Wq = (const float*)d_in[1];
  const float* Wkv = (const float*)d_in[2];
  const float* Wo = (const float*)d_in[3];
  const float* qnw = (const float*)d_in[4];
  const float* knw = (const float*)d_in[5];
  float* out = (float*)d_out;
  char* ws = (char*)d_ws;

  ushort* xb = (ushort*)(ws);                    // 16,777,216 B (bf16 x)
  ushort* wqt = (ushort*)(ws + 16777216);        //  8,388,608 B (Wq^T)
  ushort* wkvt = (ushort*)(ws + 25165824);       //  4,194,304 B (Wkv^T)
  ushort* wot = (ushort*)(ws + 29360128);        //  8,388,608 B (Wo^T)
  ushort* qraw = (ushort*)(ws + 37748736);       // 16,777,216 B
  ushort* kvraw = (ushort*)(ws + 54525952);      //  8,388,608 B
  ushort* kh = (ushort*)(ws + 62914560);         //  4,194,304 B
  ushort* vtp = (ushort*)(ws + 67108864);        //  4,194,304 B
  float2* rope = (float2*)(ws + 71303168);       //  1,048,576 B  (total 72,351,744)
  ushort* qh = xb;      // alias: xb dead after projections
  ushort* attnb = qraw; // alias: qraw dead after norm_rope

  float attn_scale = 1.0f / ((0.1f * logf(4.0f) + 1.0f) * sqrtf(128.0f));

  build_rope<<<512, 256, 0, stream>>>(rope);
  cvt_f32_bf16<<<8192, 256, 0, stream>>>((const float4*)x, xb, 2097152);
  tconv<<<dim3(32, 32), 256, 0, stream>>>(Wq, wqt, 2048, 2048);
  tconv<<<dim3(16, 32), 256, 0, stream>>>(Wkv, wkvt, 2048, 1024);
  tconv<<<dim3(32, 32), 256, 0, stream>>>(Wo, wot, 2048, 2048);
  gemm_bt<1><<<dim3(16, 32), 256, 0, stream>>>(xb, wqt, qraw, 4096, 2048, 2048);
  gemm_bt<1><<<dim3(8, 32), 256, 0, stream>>>(xb, wkvt, kvraw, 4096, 1024, 2048);
  norm_rope<<<20480, 256, 0, stream>>>(qraw, kvraw, qnw, knw, rope, qh, kh, attn_scale);
  tv_kernel<<<dim3(32, 16), 256, 0, stream>>>(kvraw, vtp);
  attn_fwd<<<dim3(16, 16, 2), 256, 0, stream>>>(qh, kh, vtp, attnb);
  gemm_bt<0><<<dim3(16, 32), 256, 0, stream>>>(attnb, wot, out, 4096, 2048, 2048);
}

// Round 2
// 305.849 us; speedup vs baseline: 1.2753x; 1.2753x over previous
//
#include <hip/hip_runtime.h>
#include <cmath>

typedef float f32x4 __attribute__((ext_vector_type(4)));
typedef __bf16 bf16x8 __attribute__((ext_vector_type(8)));

#define DEV static __device__ __forceinline__

DEV unsigned short f2bf(float f) {
  unsigned int u = __builtin_bit_cast(unsigned int, f);
  u += 0x7FFFu + ((u >> 16) & 1u);
  return (unsigned short)(u >> 16);
}
DEV float bf2f(unsigned short h) {
  unsigned int u = ((unsigned int)h) << 16;
  return __builtin_bit_cast(float, u);
}
DEV f32x4 mfma16(bf16x8 a, bf16x8 b, f32x4 c) {
  return __builtin_amdgcn_mfma_f32_16x16x32_bf16(a, b, c, 0, 0, 0);
}
// async global->LDS, 16B per lane; lds dest = wave-uniform base + lane*16
DEV void dma16(const void* g, void* l) {
  __builtin_amdgcn_global_load_lds(
      (const __attribute__((address_space(1))) void*)(uintptr_t)g,
      (__attribute__((address_space(3))) void*)(unsigned int)(uintptr_t)l,
      16, 0, 0);
}

constexpr int T_SEQ = 2048;

// ---------------------------------------------------------------- rope table
__global__ __launch_bounds__(256) void build_rope(float2* __restrict__ rope) {
  int gid = blockIdx.x * 256 + threadIdx.x;
  if (gid >= T_SEQ * 64) return;
  int t = gid >> 6, i = gid & 63;
  double inv = pow(10000.0, -((double)(2 * i)) / 128.0);
  double wl = 6.283185307179586 / inv;
  double gm = (4096.0 - wl) / (4096.0 - 128.0);
  gm = gm < 0.0 ? 0.0 : (gm > 1.0 ? 1.0 : gm);
  float f = (float)(gm * inv + (1.0 - gm) * inv * 0.25);
  float th = (float)t * f;
  float s, c;
  sincosf(th, &s, &c);
  rope[gid] = make_float2(c, s);
}

// --------------------------------- fp32 -> bf16, XOR-swizzled (2048-col rows)
__global__ __launch_bounds__(256) void cvt_f32_bf16(const float4* __restrict__ in,
                                                    ushort* __restrict__ out, int n4) {
  int i = blockIdx.x * 256 + threadIdx.x;
  if (i >= n4) return;
  float4 v = in[i];
  unsigned int lo = (unsigned int)f2bf(v.x) | ((unsigned int)f2bf(v.y) << 16);
  unsigned int hi = (unsigned int)f2bf(v.z) | ((unsigned int)f2bf(v.w) << 16);
  int row = i >> 9;                       // 512 float4 per 2048-elem row
  int e = (i * 4) & 2047;
  size_t o = ((size_t)row << 11) + (size_t)(e ^ ((row & 7) << 3));
  *(uint2*)(out + o) = make_uint2(lo, hi);
}

// --------------- fp32 RxC -> bf16 CxR transpose, XOR-swizzled output rows
__global__ __launch_bounds__(256) void tconv(const float* __restrict__ in,
                                             ushort* __restrict__ out, int R, int C) {
  __shared__ ushort tile[64][65];
  int c0 = blockIdx.x * 64, r0 = blockIdx.y * 64;
  int j = threadIdx.x & 63, i0 = threadIdx.x >> 6;
#pragma unroll
  for (int ii = 0; ii < 16; ++ii) {
    int i = i0 + ii * 4;
    tile[i][j] = f2bf(in[(size_t)(r0 + i) * C + c0 + j]);
  }
  __syncthreads();
#pragma unroll
  for (int ii = 0; ii < 16; ++ii) {
    int jr = i0 + ii * 4;
    out[(size_t)(c0 + jr) * R + ((r0 + j) ^ ((jr & 7) << 3))] = tile[j][jr];
  }
}

// ---------------- bf16 GEMM (m97 structure): C = A * Bt^T, A/Bt pre-swizzled
template <int OUT_BF16>
__global__ __launch_bounds__(256) void gemm_bt(const ushort* __restrict__ A,
                                               const ushort* __restrict__ Bt,
                                               void* __restrict__ Cv,
                                               int M, int N, int K) {
  __shared__ ushort lA[128 * 64];
  __shared__ ushort lB[128 * 64];
  const int tid = threadIdx.x;
  const int lane = tid & 63;
  const int w = tid >> 6;
  const int m0 = blockIdx.y * 128;
  const int n0 = blockIdx.x * 128;
  const int wm = (w >> 1) << 6;
  const int wn = (w & 1) << 6;

  f32x4 acc[4][4] = {};

  const size_t K2 = (size_t)K * 2;
  const char* Ab = (const char*)A + (size_t)m0 * K2;
  const char* Bb = (const char*)Bt + (size_t)n0 * K2;
  const int drow = w * 32 + (lane >> 3);
  const int dcb = (lane & 7) * 16;

  for (int k0 = 0; k0 < K; k0 += 64) {
#pragma unroll
    for (int ii = 0; ii < 4; ++ii) {
      const int off = w * 4096 + ii * 1024;
      const size_t gofs = (size_t)(drow + ii * 8) * K2 + (size_t)k0 * 2 + dcb;
      dma16(Ab + gofs, (char*)lA + off);
      dma16(Bb + gofs, (char*)lB + off);
    }
    __syncthreads();  // drains vmcnt -> DMA complete
#pragma unroll
    for (int kc = 0; kc < 2; ++kc) {
      bf16x8 a[4], bb[4];
#pragma unroll
      for (int mt = 0; mt < 4; ++mt) {
        int row = wm + mt * 16 + (lane & 15);
        int byo = kc * 64 + ((lane >> 4) << 4);
        a[mt] = *(const bf16x8*)((const char*)lA + row * 128 + (byo ^ ((row & 7) << 4)));
      }
#pragma unroll
      for (int nt = 0; nt < 4; ++nt) {
        int row = wn + nt * 16 + (lane & 15);
        int byo = kc * 64 + ((lane >> 4) << 4);
        bb[nt] = *(const bf16x8*)((const char*)lB + row * 128 + (byo ^ ((row & 7) << 4)));
      }
#pragma unroll
      for (int mt = 0; mt < 4; ++mt)
#pragma unroll
        for (int nt = 0; nt < 4; ++nt)
          acc[mt][nt] = mfma16(a[mt], bb[nt], acc[mt][nt]);
    }
    __syncthreads();
  }

  const int rr = (lane >> 4) << 2;
  const int cc = lane & 15;
  if (OUT_BF16) {
    ushort* C = (ushort*)Cv;
#pragma unroll
    for (int mt = 0; mt < 4; ++mt)
#pragma unroll
      for (int nt = 0; nt < 4; ++nt)
#pragma unroll
        for (int j = 0; j < 4; ++j) {
          int r = m0 + wm + mt * 16 + rr + j;
          int c = n0 + wn + nt * 16 + cc;
          C[(size_t)r * N + c] = f2bf(acc[mt][nt][j]);
        }
  } else {
    float* C = (float*)Cv;
#pragma unroll
    for (int mt = 0; mt < 4; ++mt)
#pragma unroll
      for (int nt = 0; nt < 4; ++nt)
#pragma unroll
        for (int j = 0; j < 4; ++j) {
          int r = m0 + wm + mt * 16 + rr + j;
          int c = n0 + wn + nt * 16 + cc;
          C[(size_t)r * N + c] = acc[mt][nt][j];
        }
  }
}

// ------------- RMSNorm + YaRN RoPE epilogue; qkv row stride 3072 (fused GEMM)
__global__ __launch_bounds__(256) void norm_rope(const ushort* __restrict__ qkv,
                                                 const float* __restrict__ qw,
                                                 const float* __restrict__ kw,
                                                 const float2* __restrict__ rope,
                                                 ushort* __restrict__ qout,
                                                 ushort* __restrict__ kout,
                                                 float attn_scale) {
  const int w = threadIdx.x >> 6, lane = threadIdx.x & 63;
  const int vi = blockIdx.x * 4 + w;
  const ushort* src;
  const float* wt;
  ushort* dst;
  float extra;
  int t, bb;
  if (vi < 65536) {
    int row = vi >> 4, H = vi & 15;
    bb = row >> 11;
    t = row & 2047;
    src = qkv + (size_t)row * 3072 + H * 128 + lane * 2;
    wt = qw;
    extra = attn_scale;
    dst = qout + ((size_t)(bb * 16 + H) * T_SEQ + t) * 128 + lane * 2;  // linear
  } else {
    int vi2 = vi - 65536;
    int row = vi2 >> 2, gg = vi2 & 3;
    bb = row >> 11;
    t = row & 2047;
    src = qkv + (size_t)row * 3072 + 2048 + gg * 128 + lane * 2;
    wt = kw;
    extra = 1.f;
    dst = kout + ((size_t)(bb * 4 + gg) * T_SEQ + t) * 128 +
          ((lane * 2) ^ ((t & 7) << 3));  // pre-swizzled for DMA staging
  }
  float x0 = bf2f(src[0]), x1 = bf2f(src[1]);
  float ss = x0 * x0 + x1 * x1;
#pragma unroll
  for (int d = 1; d < 64; d <<= 1) ss += __shfl_xor(ss, d, 64);
  float sc = rsqrtf(ss * (1.f / 128.f) + 1.1920929e-7f);
  float w0 = wt[lane * 2], w1 = wt[lane * 2 + 1];
  float xn0 = x0 * sc * w0, xn1 = x1 * sc * w1;
  float p0 = __shfl_xor(xn0, 32, 64), p1 = __shfl_xor(xn1, 32, 64);
  float r0 = lane < 32 ? -p0 : p0;
  float r1 = lane < 32 ? -p1 : p1;
  int i0 = (lane * 2) & 63;
  float2 cs0 = rope[t * 64 + i0];
  float2 cs1 = rope[t * 64 + i0 + 1];
  float o0 = (xn0 * cs0.x + r0 * cs0.y) * extra;
  float o1 = (xn1 * cs1.x + r1 * cs1.y) * extra;
  unsigned int pk = (unsigned int)f2bf(o0) | ((unsigned int)f2bf(o1) << 16);
  *(unsigned int*)dst = pk;
}

// ------------- V transpose: (b,t,g,d)->(b,g,d,t), pre-swizzled output rows
__global__ __launch_bounds__(256) void tv_kernel(const ushort* __restrict__ qkv,
                                                 ushort* __restrict__ vt) {
  __shared__ ushort tile[64][65];
  int t0 = blockIdx.x * 64;
  int y = blockIdx.y;  // ((b*4+g)*2 + dh)
  int dh = y & 1, bg = y >> 1;
  int bb = bg >> 2, g = bg & 3;
  int j = threadIdx.x & 63, i0 = threadIdx.x >> 6;
#pragma unroll
  for (int ii = 0; ii < 16; ++ii) {
    int i = i0 + ii * 4;
    tile[i][j] = qkv[(size_t)(bb * T_SEQ + t0 + i) * 3072 + 2560 + g * 128 + dh * 64 + j];
  }
  __syncthreads();
#pragma unroll
  for (int ii = 0; ii < 16; ++ii) {
    int jr = i0 + ii * 4;
    vt[((size_t)bg * 128 + dh * 64 + jr) * T_SEQ + ((t0 + j) ^ ((jr & 7) << 3))] = tile[j][jr];
  }
}

// ----------------------------------------------------------- flash attention
// 1-D grid, balanced long+short Q-tile pairing; dbuf DMA staging, counted vmcnt
__global__ __launch_bounds__(256) void attn_fwd(const ushort* __restrict__ qh,
                                                const ushort* __restrict__ kh,
                                                const ushort* __restrict__ vt,
                                                ushort* __restrict__ o) {
  const int f = blockIdx.x;             // 512 blocks
  const int x16 = f >> 5, bh = f & 31;
  const int b = bh >> 4, H = bh & 15;
  const int qt = (x16 < 8) ? (15 - x16) : (x16 - 8);  // pair qt with 15-qt per CU
  const int g = H & 3;
  const int tid = threadIdx.x, lane = tid & 63, w = tid >> 6;
  const int wrow0 = qt * 128 + w * 32;

  __shared__ ushort lK[2][64 * 128];   // 2 x 16KB swizzled, rows = kv
  __shared__ ushort lV[2][128 * 64];   // 2 x 16KB swizzled, rows = d (V^T)
  __shared__ ushort lP[4 * 32 * 64];   // 16KB, per-wave private

  bf16x8 qf[2][4];
#pragma unroll
  for (int mt = 0; mt < 2; ++mt) {
    const ushort* qb = qh + ((size_t)(b * 16 + H) * T_SEQ + wrow0 + mt * 16 + (lane & 15)) * 128 +
                       ((lane >> 4) << 3);
#pragma unroll
    for (int kc = 0; kc < 4; ++kc) qf[mt][kc] = *(const bf16x8*)(qb + kc * 32);
  }

  f32x4 oacc[2][8] = {};
  float mrow[2][4], lrow[2][4];
#pragma unroll
  for (int mt = 0; mt < 2; ++mt)
#pragma unroll
    for (int jj = 0; jj < 4; ++jj) {
      mrow[mt][jj] = -INFINITY;
      lrow[mt][jj] = 0.f;
    }

  const char* kpl = (const char*)(kh + (size_t)(b * 4 + g) * T_SEQ * 128);
  const char* vpl = (const char*)(vt + (size_t)(b * 4 + g) * 128 * T_SEQ);
  const int jmax = 2 * qt + 1;

  auto stage = [&](int j, int bi) {
#pragma unroll
    for (int ii = 0; ii < 4; ++ii) {
      const int off = w * 4096 + ii * 1024;
      dma16(kpl + (size_t)j * 16384 + off + lane * 16, (char*)lK + bi * 16384 + off);
      const int vrow = w * 32 + ii * 8 + (lane >> 3);
      dma16(vpl + (size_t)vrow * (T_SEQ * 2) + j * 128 + (lane & 7) * 16,
            (char*)lV + bi * 16384 + off);
    }
  };

  stage(0, 0);

  for (int j = 0; j <= jmax; ++j) {
    const int cur = j & 1;
    if (j < jmax) {
      stage(j + 1, cur ^ 1);                         // prefetch next tile
      asm volatile("s_waitcnt vmcnt(8)" ::: "memory");  // tile j landed, j+1 in flight
    } else {
      asm volatile("s_waitcnt vmcnt(0)" ::: "memory");
    }
    __builtin_amdgcn_s_barrier();
    __builtin_amdgcn_sched_barrier(0);

    const char* lKc = (const char*)lK + cur * 16384;
    const char* lVc = (const char*)lV + cur * 16384;

    // S = Q K^T  (per wave: 32 x 64)
    f32x4 s[2][4];
#pragma unroll
    for (int nt = 0; nt < 4; ++nt) {
      bf16x8 kf[4];
      int krow = nt * 16 + (lane & 15);
#pragma unroll
      for (int kc = 0; kc < 4; ++kc) {
        int byo = kc * 64 + ((lane >> 4) << 4);
        kf[kc] = *(const bf16x8*)(lKc + krow * 256 + (byo ^ ((krow & 7) << 4)));
      }
#pragma unroll
      for (int mt = 0; mt < 2; ++mt) {
        f32x4 a = {0.f, 0.f, 0.f, 0.f};
#pragma unroll
        for (int kc = 0; kc < 4; ++kc) a = mfma16(qf[mt][kc], kf[kc], a);
        s[mt][nt] = a;
      }
    }

    // causal mask (only the top two KV tiles can cross the diagonal)
    if (j >= jmax - 1) {
#pragma unroll
      for (int mt = 0; mt < 2; ++mt)
#pragma unroll
        for (int nt = 0; nt < 4; ++nt)
#pragma unroll
          for (int jj = 0; jj < 4; ++jj) {
            int row = wrow0 + mt * 16 + ((lane >> 4) << 2) + jj;
            int col = j * 64 + nt * 16 + (lane & 15);
            if (col > row) s[mt][nt][jj] = -3.0e38f;
          }
    }

    // online softmax
#pragma unroll
    for (int mt = 0; mt < 2; ++mt)
#pragma unroll
      for (int jj = 0; jj < 4; ++jj) {
        float pm = fmaxf(fmaxf(s[mt][0][jj], s[mt][1][jj]), fmaxf(s[mt][2][jj], s[mt][3][jj]));
#pragma unroll
        for (int d = 1; d < 16; d <<= 1) pm = fmaxf(pm, __shfl_xor(pm, d, 64));
        float mn = fmaxf(mrow[mt][jj], pm);
        float rsc = __expf(mrow[mt][jj] - mn);
        mrow[mt][jj] = mn;
        float ps = 0.f;
#pragma unroll
        for (int nt = 0; nt < 4; ++nt) {
          float p = __expf(s[mt][nt][jj] - mn);
          s[mt][nt][jj] = p;
          ps += p;
        }
#pragma unroll
        for (int d = 1; d < 16; d <<= 1) ps += __shfl_xor(ps, d, 64);
        lrow[mt][jj] = lrow[mt][jj] * rsc + ps;
#pragma unroll
        for (int dt = 0; dt < 8; ++dt) oacc[mt][dt][jj] *= rsc;
      }

    // P -> LDS (bf16, swizzled), per-wave private region -> no barrier needed
#pragma unroll
    for (int mt = 0; mt < 2; ++mt)
#pragma unroll
      for (int nt = 0; nt < 4; ++nt)
#pragma unroll
        for (int jj = 0; jj < 4; ++jj) {
          int prow = mt * 16 + ((lane >> 4) << 2) + jj;
          int pcb = (nt * 16 + (lane & 15)) * 2;
          *(ushort*)((char*)lP + w * 4096 + prow * 128 + (pcb ^ ((prow & 7) << 4))) =
              f2bf(s[mt][nt][jj]);
        }

    // O += P V
#pragma unroll
    for (int kc2 = 0; kc2 < 2; ++kc2) {
      bf16x8 pa[2];
#pragma unroll
      for (int mt = 0; mt < 2; ++mt) {
        int prow = mt * 16 + (lane & 15);
        int pbo = kc2 * 64 + ((lane >> 4) << 4);
        pa[mt] = *(const bf16x8*)((char*)lP + w * 4096 + prow * 128 + (pbo ^ ((prow & 7) << 4)));
      }
#pragma unroll
      for (int dt = 0; dt < 8; ++dt) {
        int vrow = dt * 16 + (lane & 15);
        int vbo = kc2 * 64 + ((lane >> 4) << 4);
        bf16x8 vf = *(const bf16x8*)(lVc + vrow * 128 + (vbo ^ ((vrow & 7) << 4)));
#pragma unroll
        for (int mt = 0; mt < 2; ++mt) oacc[mt][dt] = mfma16(pa[mt], vf, oacc[mt][dt]);
      }
    }

    __builtin_amdgcn_sched_barrier(0);
    __builtin_amdgcn_s_barrier();  // all waves done with buf[cur] before overwrite
  }

  // write O (b, t, H*128+d) bf16, pre-swizzled rows for the Wo GEMM's DMA
#pragma unroll
  for (int mt = 0; mt < 2; ++mt) {
    float inv[4];
#pragma unroll
    for (int jj = 0; jj < 4; ++jj) inv[jj] = 1.f / lrow[mt][jj];
#pragma unroll
    for (int dt = 0; dt < 8; ++dt)
#pragma unroll
      for (int jj = 0; jj < 4; ++jj) {
        int row = wrow0 + mt * 16 + ((lane >> 4) << 2) + jj;
        int col = H * 128 + dt * 16 + (lane & 15);
        o[(size_t)(b * T_SEQ + row) * 2048 + (col ^ ((row & 7) << 3))] =
            f2bf(oacc[mt][dt][jj] * inv[jj]);
      }
  }
}

// ---------------------------------------------------------------------------
extern "C" void kernel_launch(void* const* d_in, const int* in_sizes, int n_in,
                              void* d_out, int out_size, void* d_ws, size_t ws_size,
                              hipStream_t stream) {
  (void)in_sizes; (void)n_in; (void)out_size; (void)ws_size;
  const float* x = (const float*)d_in[0];
  const float* Wq = (const float*)d_in[1];
  const float* Wkv = (const float*)d_in[2];
  const float* Wo = (const float*)d_in[3];
  const float* qnw = (const float*)d_in[4];
  const float* knw = (const float*)d_in[5];
  float* out = (float*)d_out;
  char* ws = (char*)d_ws;

  ushort* xb = (ushort*)(ws);                 // 16,777,216 B (bf16 x, swizzled)
  ushort* wqkv = (ushort*)(ws + 16777216);    // 12,582,912 B (Wq^T ++ Wkv^T, swizzled)
  ushort* wot = (ushort*)(ws + 29360128);     //  8,388,608 B (Wo^T, swizzled)
  ushort* qkvraw = (ushort*)(ws + 37748736);  // 25,165,824 B (4096 x 3072, linear)
  ushort* kh = (ushort*)(ws + 62914560);      //  4,194,304 B (swizzled)
  ushort* vtp = (ushort*)(ws + 67108864);     //  4,194,304 B (swizzled)
  float2* rope = (float2*)(ws + 71303168);    //  1,048,576 B (total 72,351,744)
  ushort* qh = xb;        // alias: xb dead after projection GEMM
  ushort* attnb = qkvraw; // alias: qkvraw dead after norm_rope + tv

  float attn_scale = 1.0f / ((0.1f * logf(4.0f) + 1.0f) * sqrtf(128.0f));

  build_rope<<<512, 256, 0, stream>>>(rope);
  cvt_f32_bf16<<<8192, 256, 0, stream>>>((const float4*)x, xb, 2097152);
  tconv<<<dim3(32, 32), 256, 0, stream>>>(Wq, wqkv, 2048, 2048);
  tconv<<<dim3(16, 32), 256, 0, stream>>>(Wkv, wqkv + (size_t)2048 * 2048, 2048, 1024);
  tconv<<<dim3(32, 32), 256, 0, stream>>>(Wo, wot, 2048, 2048);
  gemm_bt<1><<<dim3(24, 32), 256, 0, stream>>>(xb, wqkv, qkvraw, 4096, 3072, 2048);
  norm_rope<<<20480, 256, 0, stream>>>(qkvraw, qnw, knw, rope, qh, kh, attn_scale);
  tv_kernel<<<dim3(32, 16), 256, 0, stream>>>(qkvraw, vtp);
  attn_fwd<<<512, 256, 0, stream>>>(qh, kh, vtp, attnb);
  gemm_bt<0><<<dim3(16, 32), 256, 0, stream>>>(attnb, wot, out, 4096, 2048, 2048);
}

// Round 3
// 227.459 us; speedup vs baseline: 1.7148x; 1.3446x over previous
//
#include <hip/hip_runtime.h>
#include <cmath>

typedef float f32x4 __attribute__((ext_vector_type(4)));
typedef __bf16 bf16x8 __attribute__((ext_vector_type(8)));

#define DEV static __device__ __forceinline__

DEV unsigned short f2bf(float f) {
  unsigned int u = __builtin_bit_cast(unsigned int, f);
  u += 0x7FFFu + ((u >> 16) & 1u);
  return (unsigned short)(u >> 16);
}
DEV float bf2f(unsigned short h) {
  unsigned int u = ((unsigned int)h) << 16;
  return __builtin_bit_cast(float, u);
}
DEV f32x4 mfma16(bf16x8 a, bf16x8 b, f32x4 c) {
  return __builtin_amdgcn_mfma_f32_16x16x32_bf16(a, b, c, 0, 0, 0);
}
// async global->LDS, 16B per lane; lds dest = wave-uniform base (+ lane*16 by HW)
DEV void dma16(const void* g, void* l) {
  __builtin_amdgcn_global_load_lds(
      (const __attribute__((address_space(1))) void*)(uintptr_t)g,
      (__attribute__((address_space(3))) void*)(unsigned int)(uintptr_t)l,
      16, 0, 0);
}

constexpr int T_SEQ = 2048;

// ---------------------------------------------------------------- rope table
__global__ __launch_bounds__(256) void build_rope(float2* __restrict__ rope) {
  int gid = blockIdx.x * 256 + threadIdx.x;
  if (gid >= T_SEQ * 64) return;
  int t = gid >> 6, i = gid & 63;
  double inv = pow(10000.0, -((double)(2 * i)) / 128.0);
  double wl = 6.283185307179586 / inv;
  double gm = (4096.0 - wl) / (4096.0 - 128.0);
  gm = gm < 0.0 ? 0.0 : (gm > 1.0 ? 1.0 : gm);
  float f = (float)(gm * inv + (1.0 - gm) * inv * 0.25);
  float th = (float)t * f;
  float s, c;
  sincosf(th, &s, &c);
  rope[gid] = make_float2(c, s);
}

// --------------------------------- fp32 -> bf16, XOR-swizzled (2048-col rows)
__global__ __launch_bounds__(256) void cvt_f32_bf16(const float4* __restrict__ in,
                                                    ushort* __restrict__ out, int n4) {
  int i = blockIdx.x * 256 + threadIdx.x;
  if (i >= n4) return;
  float4 v = in[i];
  unsigned int lo = (unsigned int)f2bf(v.x) | ((unsigned int)f2bf(v.y) << 16);
  unsigned int hi = (unsigned int)f2bf(v.z) | ((unsigned int)f2bf(v.w) << 16);
  int row = i >> 9;                       // 512 float4 per 2048-elem row
  int e = (i * 4) & 2047;
  size_t o = ((size_t)row << 11) + (size_t)(e ^ ((row & 7) << 3));
  *(uint2*)(out + o) = make_uint2(lo, hi);
}

// --------------- fp32 RxC -> bf16 CxR transpose, XOR-swizzled output rows
__global__ __launch_bounds__(256) void tconv(const float* __restrict__ in,
                                             ushort* __restrict__ out, int R, int C) {
  __shared__ ushort tile[64][65];
  int c0 = blockIdx.x * 64, r0 = blockIdx.y * 64;
  int j = threadIdx.x & 63, i0 = threadIdx.x >> 6;
#pragma unroll
  for (int ii = 0; ii < 16; ++ii) {
    int i = i0 + ii * 4;
    tile[i][j] = f2bf(in[(size_t)(r0 + i) * C + c0 + j]);
  }
  __syncthreads();
#pragma unroll
  for (int ii = 0; ii < 16; ++ii) {
    int jr = i0 + ii * 4;
    out[(size_t)(c0 + jr) * R + ((r0 + j) ^ ((jr & 7) << 3))] = tile[j][jr];
  }
}

// ---------------- bf16 GEMM (m97 structure): C = A * Bt^T, A/Bt pre-swizzled
template <int OUT_BF16>
__global__ __launch_bounds__(256) void gemm_bt(const ushort* __restrict__ A,
                                               const ushort* __restrict__ Bt,
                                               void* __restrict__ Cv,
                                               int M, int N, int K) {
  __shared__ ushort lA[128 * 64];
  __shared__ ushort lB[128 * 64];
  const int tid = threadIdx.x;
  const int lane = tid & 63;
  const int w = tid >> 6;
  const int m0 = blockIdx.y * 128;
  const int n0 = blockIdx.x * 128;
  const int wm = (w >> 1) << 6;
  const int wn = (w & 1) << 6;

  f32x4 acc[4][4] = {};

  const size_t K2 = (size_t)K * 2;
  const char* Ab = (const char*)A + (size_t)m0 * K2;
  const char* Bb = (const char*)Bt + (size_t)n0 * K2;
  const int drow = w * 32 + (lane >> 3);
  const int dcb = (lane & 7) * 16;

  for (int k0 = 0; k0 < K; k0 += 64) {
#pragma unroll
    for (int ii = 0; ii < 4; ++ii) {
      const int off = w * 4096 + ii * 1024;
      const size_t gofs = (size_t)(drow + ii * 8) * K2 + (size_t)k0 * 2 + dcb;
      dma16(Ab + gofs, (char*)lA + off);
      dma16(Bb + gofs, (char*)lB + off);
    }
    __syncthreads();  // drains vmcnt -> DMA complete
#pragma unroll
    for (int kc = 0; kc < 2; ++kc) {
      bf16x8 a[4], bb[4];
#pragma unroll
      for (int mt = 0; mt < 4; ++mt) {
        int row = wm + mt * 16 + (lane & 15);
        int byo = kc * 64 + ((lane >> 4) << 4);
        a[mt] = *(const bf16x8*)((const char*)lA + row * 128 + (byo ^ ((row & 7) << 4)));
      }
#pragma unroll
      for (int nt = 0; nt < 4; ++nt) {
        int row = wn + nt * 16 + (lane & 15);
        int byo = kc * 64 + ((lane >> 4) << 4);
        bb[nt] = *(const bf16x8*)((const char*)lB + row * 128 + (byo ^ ((row & 7) << 4)));
      }
#pragma unroll
      for (int mt = 0; mt < 4; ++mt)
#pragma unroll
        for (int nt = 0; nt < 4; ++nt)
          acc[mt][nt] = mfma16(a[mt], bb[nt], acc[mt][nt]);
    }
    __syncthreads();
  }

  const int rr = (lane >> 4) << 2;
  const int cc = lane & 15;
  if (OUT_BF16) {
    ushort* C = (ushort*)Cv;
#pragma unroll
    for (int mt = 0; mt < 4; ++mt)
#pragma unroll
      for (int nt = 0; nt < 4; ++nt)
#pragma unroll
        for (int j = 0; j < 4; ++j) {
          int r = m0 + wm + mt * 16 + rr + j;
          int c = n0 + wn + nt * 16 + cc;
          C[(size_t)r * N + c] = f2bf(acc[mt][nt][j]);
        }
  } else {
    float* C = (float*)Cv;
#pragma unroll
    for (int mt = 0; mt < 4; ++mt)
#pragma unroll
      for (int nt = 0; nt < 4; ++nt)
#pragma unroll
        for (int j = 0; j < 4; ++j) {
          int r = m0 + wm + mt * 16 + rr + j;
          int c = n0 + wn + nt * 16 + cc;
          C[(size_t)r * N + c] = acc[mt][nt][j];
        }
  }
}

// ------------- RMSNorm + YaRN RoPE epilogue; qkv row stride 3072 (fused GEMM)
__global__ __launch_bounds__(256) void norm_rope(const ushort* __restrict__ qkv,
                                                 const float* __restrict__ qw,
                                                 const float* __restrict__ kw,
                                                 const float2* __restrict__ rope,
                                                 ushort* __restrict__ qout,
                                                 ushort* __restrict__ kout,
                                                 float attn_scale) {
  const int w = threadIdx.x >> 6, lane = threadIdx.x & 63;
  const int vi = blockIdx.x * 4 + w;
  const ushort* src;
  const float* wt;
  ushort* dst;
  float extra;
  int t, bb;
  if (vi < 65536) {
    int row = vi >> 4, H = vi & 15;
    bb = row >> 11;
    t = row & 2047;
    src = qkv + (size_t)row * 3072 + H * 128 + lane * 2;
    wt = qw;
    extra = attn_scale;
    dst = qout + ((size_t)(bb * 16 + H) * T_SEQ + t) * 128 + lane * 2;  // linear
  } else {
    int vi2 = vi - 65536;
    int row = vi2 >> 2, gg = vi2 & 3;
    bb = row >> 11;
    t = row & 2047;
    src = qkv + (size_t)row * 3072 + 2048 + gg * 128 + lane * 2;
    wt = kw;
    extra = 1.f;
    dst = kout + ((size_t)(bb * 4 + gg) * T_SEQ + t) * 128 +
          ((lane * 2) ^ ((t & 7) << 3));  // pre-swizzled for DMA staging
  }
  float x0 = bf2f(src[0]), x1 = bf2f(src[1]);
  float ss = x0 * x0 + x1 * x1;
#pragma unroll
  for (int d = 1; d < 64; d <<= 1) ss += __shfl_xor(ss, d, 64);
  float sc = rsqrtf(ss * (1.f / 128.f) + 1.1920929e-7f);
  float w0 = wt[lane * 2], w1 = wt[lane * 2 + 1];
  float xn0 = x0 * sc * w0, xn1 = x1 * sc * w1;
  float p0 = __shfl_xor(xn0, 32, 64), p1 = __shfl_xor(xn1, 32, 64);
  float r0 = lane < 32 ? -p0 : p0;
  float r1 = lane < 32 ? -p1 : p1;
  int i0 = (lane * 2) & 63;
  float2 cs0 = rope[t * 64 + i0];
  float2 cs1 = rope[t * 64 + i0 + 1];
  float o0 = (xn0 * cs0.x + r0 * cs0.y) * extra;
  float o1 = (xn1 * cs1.x + r1 * cs1.y) * extra;
  unsigned int pk = (unsigned int)f2bf(o0) | ((unsigned int)f2bf(o1) << 16);
  *(unsigned int*)dst = pk;
}

// ------------- V transpose: (b,t,g,d)->(b,g,d,t), pre-swizzled output rows
__global__ __launch_bounds__(256) void tv_kernel(const ushort* __restrict__ qkv,
                                                 ushort* __restrict__ vt) {
  __shared__ ushort tile[64][65];
  int t0 = blockIdx.x * 64;
  int y = blockIdx.y;  // ((b*4+g)*2 + dh)
  int dh = y & 1, bg = y >> 1;
  int bb = bg >> 2, g = bg & 3;
  int j = threadIdx.x & 63, i0 = threadIdx.x >> 6;
#pragma unroll
  for (int ii = 0; ii < 16; ++ii) {
    int i = i0 + ii * 4;
    tile[i][j] = qkv[(size_t)(bb * T_SEQ + t0 + i) * 3072 + 2560 + g * 128 + dh * 64 + j];
  }
  __syncthreads();
#pragma unroll
  for (int ii = 0; ii < 16; ++ii) {
    int jr = i0 + ii * 4;
    vt[((size_t)bg * 128 + dh * 64 + jr) * T_SEQ + ((t0 + j) ^ ((jr & 7) << 3))] = tile[j][jr];
  }
}

// ----------------------------------------------------------- flash attention
// 64-row Q-tiles, 4 waves (16 rows/wave), 1024 blocks, 40KB LDS -> 4 blocks/CU.
// Swapped QK^T (S^T in regs, lane-local rows), defer-max, single-buffer K/V.
__global__ __launch_bounds__(256, 4) void attn_fwd(const ushort* __restrict__ qh,
                                                   const ushort* __restrict__ kh,
                                                   const ushort* __restrict__ vt,
                                                   ushort* __restrict__ o) {
  const int f = blockIdx.x;  // 1024 blocks
  const int r = f >> 8, kk = (f >> 5) & 7, bh = f & 31;
  // per-CU residency rounds sum to 66 iters under mod-256 round-robin dispatch
  const int qt = (r == 0) ? (31 - kk) : (r == 1) ? (16 + kk) : (r == 2) ? (15 - kk) : kk;
  const int b = bh >> 4, H = bh & 15;
  const int g = H & 3;
  const int tid = threadIdx.x, lane = tid & 63, w = tid >> 6;
  const int wrow0 = qt * 64 + w * 16;

  __shared__ ushort lK[64 * 128];    // 16KB swizzled, rows = kv
  __shared__ ushort lV[128 * 64];    // 16KB swizzled, rows = d (V^T)
  __shared__ ushort lP[4 * 16 * 64]; // 8KB, per-wave private 16x64

  bf16x8 qf[4];
  {
    const ushort* qb = qh + ((size_t)(b * 16 + H) * T_SEQ + wrow0 + (lane & 15)) * 128 +
                       ((lane >> 4) << 3);
#pragma unroll
    for (int kc = 0; kc < 4; ++kc) qf[kc] = *(const bf16x8*)(qb + kc * 32);
  }

  f32x4 oacc[8] = {};
  float mrow = -INFINITY, lrow = 0.f;

  const char* kpl = (const char*)(kh + (size_t)(b * 4 + g) * T_SEQ * 128);
  const char* vpl = (const char*)(vt + (size_t)(b * 4 + g) * 128 * T_SEQ);

  auto stage = [&](int j) {
#pragma unroll
    for (int ii = 0; ii < 4; ++ii) {
      const int off = w * 4096 + ii * 1024;
      dma16(kpl + (size_t)j * 16384 + off + lane * 16, (char*)lK + off);
      const int vrow = w * 32 + ii * 8 + (lane >> 3);
      dma16(vpl + (size_t)vrow * (T_SEQ * 2) + j * 128 + (lane & 7) * 16, (char*)lV + off);
    }
  };

  stage(0);

  const int qrow = wrow0 + (lane & 15);   // this lane's q row (qc form)
  const int rsel = ((lane >> 4) << 2);    // oacc row base (row form)

  for (int j = 0; j <= qt; ++j) {
    asm volatile("s_waitcnt vmcnt(0)" ::: "memory");
    __builtin_amdgcn_s_barrier();
    __builtin_amdgcn_sched_barrier(0);

    // S^T = K Q^T (per wave: 64 kv x 16 q); lane holds 16 k-slots of row qrow
    f32x4 s[4];
#pragma unroll
    for (int nt = 0; nt < 4; ++nt) {
      bf16x8 kf[4];
      int krow = nt * 16 + (lane & 15);
#pragma unroll
      for (int kc = 0; kc < 4; ++kc) {
        int byo = kc * 64 + ((lane >> 4) << 4);
        kf[kc] = *(const bf16x8*)((const char*)lK + krow * 256 + (byo ^ ((krow & 7) << 4)));
      }
      f32x4 a = {0.f, 0.f, 0.f, 0.f};
#pragma unroll
      for (int kc = 0; kc < 4; ++kc) a = mfma16(kf[kc], qf[kc], a);
      s[nt] = a;
    }

    // causal mask: only the final KV tile crosses the diagonal
    if (j == qt) {
#pragma unroll
      for (int nt = 0; nt < 4; ++nt)
#pragma unroll
        for (int jj = 0; jj < 4; ++jj) {
          int col = j * 64 + nt * 16 + ((lane >> 4) << 2) + jj;
          if (col > qrow) s[nt][jj] = -3.0e38f;
        }
    }

    // in-lane row max (16 values) + 2-step cross-group reduce
    float pm0 = fmaxf(fmaxf(s[0][0], s[0][1]), fmaxf(s[0][2], s[0][3]));
    float pm1 = fmaxf(fmaxf(s[1][0], s[1][1]), fmaxf(s[1][2], s[1][3]));
    float pm2 = fmaxf(fmaxf(s[2][0], s[2][1]), fmaxf(s[2][2], s[2][3]));
    float pm3 = fmaxf(fmaxf(s[3][0], s[3][1]), fmaxf(s[3][2], s[3][3]));
    float pm = fmaxf(fmaxf(pm0, pm1), fmaxf(pm2, pm3));
    pm = fmaxf(pm, __shfl_xor(pm, 16, 64));
    pm = fmaxf(pm, __shfl_xor(pm, 32, 64));

    float mn = mrow;
    if (!__all(pm <= mrow + 8.f)) {   // defer-max: rescale only on real growth
      mn = fmaxf(mrow, pm);
      float rsc = __expf(mrow - mn);
      mrow = mn;
      lrow *= rsc;
      float rr0 = __shfl(rsc, rsel + 0, 64);
      float rr1 = __shfl(rsc, rsel + 1, 64);
      float rr2 = __shfl(rsc, rsel + 2, 64);
      float rr3 = __shfl(rsc, rsel + 3, 64);
#pragma unroll
      for (int dt = 0; dt < 8; ++dt) {
        oacc[dt][0] *= rr0; oacc[dt][1] *= rr1;
        oacc[dt][2] *= rr2; oacc[dt][3] *= rr3;
      }
    }

    // P = exp(S - mn), in-lane sum, pack to LDS (b64 per nt)
    float ps = 0.f;
#pragma unroll
    for (int nt = 0; nt < 4; ++nt) {
      float p0 = __expf(s[nt][0] - mn);
      float p1 = __expf(s[nt][1] - mn);
      float p2 = __expf(s[nt][2] - mn);
      float p3 = __expf(s[nt][3] - mn);
      ps += (p0 + p1) + (p2 + p3);
      unsigned int w0 = (unsigned int)f2bf(p0) | ((unsigned int)f2bf(p1) << 16);
      unsigned int w1 = (unsigned int)f2bf(p2) | ((unsigned int)f2bf(p3) << 16);
      int prow = lane & 15;
      int pcb = (nt * 32 + ((lane >> 4) << 3)) ^ ((prow & 7) << 4);
      *(uint2*)((char*)lP + w * 2048 + prow * 128 + pcb) = make_uint2(w0, w1);
    }
    ps += __shfl_xor(ps, 16, 64);
    ps += __shfl_xor(ps, 32, 64);
    lrow += ps;

    // O += P V   (P per-wave private; no barrier needed between write & read)
#pragma unroll
    for (int kc2 = 0; kc2 < 2; ++kc2) {
      int prow = lane & 15;
      int pbo = kc2 * 64 + ((lane >> 4) << 4);
      bf16x8 pa = *(const bf16x8*)((char*)lP + w * 2048 + prow * 128 +
                                   (pbo ^ ((prow & 7) << 4)));
#pragma unroll
      for (int dt = 0; dt < 8; ++dt) {
        int vrow = dt * 16 + (lane & 15);
        int vbo = kc2 * 64 + ((lane >> 4) << 4);
        bf16x8 vf = *(const bf16x8*)((const char*)lV + vrow * 128 + (vbo ^ ((vrow & 7) << 4)));
        oacc[dt] = mfma16(pa, vf, oacc[dt]);
      }
    }

    __builtin_amdgcn_sched_barrier(0);
    __builtin_amdgcn_s_barrier();   // all waves done reading lK/lV
    if (j < qt) stage(j + 1);       // single-buffer refill, latency covered by
                                    // the 3 other resident blocks per CU
  }

  // write O (b, t, H*128+d) bf16, pre-swizzled rows for the Wo GEMM's DMA
  float linv = 1.f / lrow;
  float iv0 = __shfl(linv, rsel + 0, 64);
  float iv1 = __shfl(linv, rsel + 1, 64);
  float iv2 = __shfl(linv, rsel + 2, 64);
  float iv3 = __shfl(linv, rsel + 3, 64);
#pragma unroll
  for (int dt = 0; dt < 8; ++dt) {
    float v0 = oacc[dt][0] * iv0, v1 = oacc[dt][1] * iv1;
    float v2 = oacc[dt][2] * iv2, v3 = oacc[dt][3] * iv3;
    int col = H * 128 + dt * 16 + (lane & 15);
    int row = wrow0 + rsel;
    o[(size_t)(b * T_SEQ + row + 0) * 2048 + (col ^ (((row + 0) & 7) << 3))] = f2bf(v0);
    o[(size_t)(b * T_SEQ + row + 1) * 2048 + (col ^ (((row + 1) & 7) << 3))] = f2bf(v1);
    o[(size_t)(b * T_SEQ + row + 2) * 2048 + (col ^ (((row + 2) & 7) << 3))] = f2bf(v2);
    o[(size_t)(b * T_SEQ + row + 3) * 2048 + (col ^ (((row + 3) & 7) << 3))] = f2bf(v3);
  }
}

// ---------------------------------------------------------------------------
extern "C" void kernel_launch(void* const* d_in, const int* in_sizes, int n_in,
                              void* d_out, int out_size, void* d_ws, size_t ws_size,
                              hipStream_t stream) {
  (void)in_sizes; (void)n_in; (void)out_size; (void)ws_size;
  const float* x = (const float*)d_in[0];
  const float* Wq = (const float*)d_in[1];
  const float* Wkv = (const float*)d_in[2];
  const float* Wo = (const float*)d_in[3];
  const float* qnw = (const float*)d_in[4];
  const float* knw = (const float*)d_in[5];
  float* out = (float*)d_out;
  char* ws = (char*)d_ws;

  ushort* xb = (ushort*)(ws);                 // 16,777,216 B (bf16 x, swizzled)
  ushort* wqkv = (ushort*)(ws + 16777216);    // 12,582,912 B (Wq^T ++ Wkv^T, swizzled)
  ushort* wot = (ushort*)(ws + 29360128);     //  8,388,608 B (Wo^T, swizzled)
  ushort* qkvraw = (ushort*)(ws + 37748736);  // 25,165,824 B (4096 x 3072, linear)
  ushort* kh = (ushort*)(ws + 62914560);      //  4,194,304 B (swizzled)
  ushort* vtp = (ushort*)(ws + 67108864);     //  4,194,304 B (swizzled)
  float2* rope = (float2*)(ws + 71303168);    //  1,048,576 B (total 72,351,744)
  ushort* qh = xb;        // alias: xb dead after projection GEMM
  ushort* attnb = qkvraw; // alias: qkvraw dead after norm_rope + tv

  float attn_scale = 1.0f / ((0.1f * logf(4.0f) + 1.0f) * sqrtf(128.0f));

  build_rope<<<512, 256, 0, stream>>>(rope);
  cvt_f32_bf16<<<8192, 256, 0, stream>>>((const float4*)x, xb, 2097152);
  tconv<<<dim3(32, 32), 256, 0, stream>>>(Wq, wqkv, 2048, 2048);
  tconv<<<dim3(16, 32), 256, 0, stream>>>(Wkv, wqkv + (size_t)2048 * 2048, 2048, 1024);
  tconv<<<dim3(32, 32), 256, 0, stream>>>(Wo, wot, 2048, 2048);
  gemm_bt<1><<<dim3(24, 32), 256, 0, stream>>>(xb, wqkv, qkvraw, 4096, 3072, 2048);
  norm_rope<<<20480, 256, 0, stream>>>(qkvraw, qnw, knw, rope, qh, kh, attn_scale);
  tv_kernel<<<dim3(32, 16), 256, 0, stream>>>(qkvraw, vtp);
  attn_fwd<<<1024, 256, 0, stream>>>(qh, kh, vtp, attnb);
  gemm_bt<0><<<dim3(16, 32), 256, 0, stream>>>(attnb, wot, out, 4096, 2048, 2048);
}